// Round 1
// baseline (667.210 us; speedup 1.0000x reference)
//
#include <hip/hip_runtime.h>

typedef unsigned short u16;
typedef unsigned int u32;
typedef unsigned long long u64;
typedef __attribute__((ext_vector_type(8))) u16 u16x8;
typedef __attribute__((ext_vector_type(8))) __bf16 bf16x8;
typedef __attribute__((ext_vector_type(4))) float f32x4;

#define D_MODEL 1024
#define SEQ 2048
#define NBATCH 4
#define NHEAD 16
#define DKH 64

__device__ __forceinline__ u16 f2bf(float f) {
  u32 u = __builtin_bit_cast(u32, f);
  u += 0x7fffu + ((u >> 16) & 1u);   // RTNE
  return (u16)(u >> 16);
}
__device__ __forceinline__ float bf2f(u16 h) {
  u32 u = ((u32)h) << 16;
  return __builtin_bit_cast(float, u);
}
__device__ __forceinline__ f32x4 MFMA(u16x8 a, u16x8 b, f32x4 c) {
  return __builtin_amdgcn_mfma_f32_16x16x32_bf16(
      __builtin_bit_cast(bf16x8, a), __builtin_bit_cast(bf16x8, b), c, 0, 0, 0);
}

#define GLD16(gsrc, ldst)                                                     \
  __builtin_amdgcn_global_load_lds(                                           \
      (const __attribute__((address_space(1))) void*)(gsrc),                  \
      (__attribute__((address_space(3))) void*)(ldst), 16, 0, 0)

// ---------------------------------------------------------------------------
// fp32 -> bf16 conversion for x (8388608 elems) + Wq/Wk/Wv/Wo (1048576 each).
// One float4 per thread; exact grid (12288 blocks * 256 * 4 = 12582912 elems).
// ---------------------------------------------------------------------------
__global__ __launch_bounds__(256) void conv_all(
    const float* __restrict__ x, const float* __restrict__ wq,
    const float* __restrict__ wk, const float* __restrict__ wv,
    const float* __restrict__ wo, u16* __restrict__ xb, u16* __restrict__ wqb,
    u16* __restrict__ wkb, u16* __restrict__ wvb, u16* __restrict__ wob) {
  long qd = (long)blockIdx.x * 256 + threadIdx.x;
  long e = qd << 2;
  const float* src;
  u16* dst;
  long off;
  if (e < 8388608L) {
    src = x; dst = xb; off = e;
  } else {
    long j = e - 8388608L;
    int w = (int)(j >> 20);
    off = j & 1048575L;
    src = (w == 0) ? wq : (w == 1) ? wk : (w == 2) ? wv : wo;
    dst = (w == 0) ? wqb : (w == 1) ? wkb : (w == 2) ? wvb : wob;
  }
  float4 v = *(const float4*)(src + off);
  u32 lo32 = (u32)f2bf(v.x) | ((u32)f2bf(v.y) << 16);
  u32 hi32 = (u32)f2bf(v.z) | ((u32)f2bf(v.w) << 16);
  *(u64*)(dst + off) = (u64)lo32 | ((u64)hi32 << 32);
}

// ---------------------------------------------------------------------------
// C[M][N] = A[M][K] * Bm[N][K]^T   (both K-contiguous; bf16 in, fp32 accum)
// m97 structure: 128x128 tile, BK=64, 256 thr (4 waves, each 64x64),
// global_load_lds width 16, 2 barriers per K-step.
// OUTF==0: bf16 out.  OUTF==1: fp32 out + bias.
// ---------------------------------------------------------------------------
template <int OUTF>
__global__ __launch_bounds__(256) void gemm_bt(
    const u16* __restrict__ A, const u16* __restrict__ Bm, u16* __restrict__ Cb,
    float* __restrict__ Cf, const float* __restrict__ bias, int M, int N,
    int K) {
  __shared__ u16 As[128 * 64];
  __shared__ u16 Bs[128 * 64];
  const int tid = threadIdx.x;
  const int lane = tid & 63, wave = tid >> 6;
  const int lo = lane & 15, g = lane >> 4;
  const int mBase = blockIdx.y * 128, nBase = blockIdx.x * 128;
  const int wr = wave >> 1, wc = wave & 1;

  f32x4 acc[4][4];
#pragma unroll
  for (int mi = 0; mi < 4; ++mi)
#pragma unroll
    for (int ni = 0; ni < 4; ++ni) acc[mi][ni] = (f32x4){0.f, 0.f, 0.f, 0.f};

  const int nK = K >> 6;
  for (int kb = 0; kb < nK; ++kb) {
    __syncthreads();  // protect LDS against previous iter's readers
    const u16* Ab = A + (size_t)mBase * K + kb * 64;
    const u16* Bb = Bm + (size_t)nBase * K + kb * 64;
#pragma unroll
    for (int i = 0; i < 4; ++i) {
      int flat = (i * 256 + tid) * 8;
      int r = flat >> 6, c = flat & 63;
      GLD16(Ab + (size_t)r * K + c, As + (i * 256 + wave * 64) * 8);
    }
#pragma unroll
    for (int i = 0; i < 4; ++i) {
      int flat = (i * 256 + tid) * 8;
      int r = flat >> 6, c = flat & 63;
      GLD16(Bb + (size_t)r * K + c, Bs + (i * 256 + wave * 64) * 8);
    }
    __syncthreads();  // drains vmcnt(0): staged data visible

#pragma unroll
    for (int kk = 0; kk < 64; kk += 32) {
      u16x8 a[4], b[4];
#pragma unroll
      for (int mi = 0; mi < 4; ++mi)
        a[mi] = *(const u16x8*)&As[(wr * 64 + mi * 16 + lo) * 64 + kk + g * 8];
#pragma unroll
      for (int ni = 0; ni < 4; ++ni)
        b[ni] = *(const u16x8*)&Bs[(wc * 64 + ni * 16 + lo) * 64 + kk + g * 8];
#pragma unroll
      for (int mi = 0; mi < 4; ++mi)
#pragma unroll
        for (int ni = 0; ni < 4; ++ni)
          acc[mi][ni] = MFMA(a[mi], b[ni], acc[mi][ni]);
    }
  }

#pragma unroll
  for (int mi = 0; mi < 4; ++mi)
#pragma unroll
    for (int ni = 0; ni < 4; ++ni) {
      int row0 = mBase + wr * 64 + mi * 16 + g * 4;
      int col = nBase + wc * 64 + ni * 16 + lo;
      float bv = 0.f;
      if constexpr (OUTF == 1) bv = bias[col];
#pragma unroll
      for (int r = 0; r < 4; ++r) {
        size_t idx = (size_t)(row0 + r) * N + col;
        if constexpr (OUTF == 0)
          Cb[idx] = f2bf(acc[mi][ni][r]);
        else
          Cf[idx] = acc[mi][ni][r] + bv;
      }
    }
}

// ---------------------------------------------------------------------------
// Flash attention (causal + pad mask), bf16 MFMA 16x16x32, swapped QK^T.
// Block = 256 thr = 4 waves; block handles one (b,h) x 64 q-rows; each wave
// owns 16 q-rows.  K read direct from global (K-contiguous frags); V read
// direct from the pre-transposed Vt (1024 x 8192) so PV B-frags are
// contiguous 16B loads.  P round-trips a per-wave XOR-swizzled LDS buffer.
// No __syncthreads anywhere.
// ---------------------------------------------------------------------------
__global__ __launch_bounds__(256) void attn_fwd(
    const u16* __restrict__ Q, const u16* __restrict__ Kmat,
    const u16* __restrict__ Vt, const int* __restrict__ mask,
    u16* __restrict__ ctx) {
  __shared__ u16 Plds[4][16 * 72];  // per-wave 16 rows x 72 (144B stride)
  const int bid = blockIdx.x;
  const int qb = bid & 31, h = (bid >> 5) & 15, b = bid >> 9;
  const int q0 = qb << 6;
  const int tid = threadIdx.x;
  const int lane = tid & 63, wave = tid >> 6;
  const int lo = lane & 15, g = lane >> 4;
  char* P = (char*)&Plds[wave][0];

  // B-operand Q fragment: lane holds Q[q = lo][dk = g*8 + j], x 2 (dk 0..63).
  const int qrow = q0 + wave * 16 + lo;  // this lane's q row (softmax owner)
  const size_t qoff = ((size_t)(b * SEQ + qrow)) * D_MODEL + h * DKH + g * 8;
  u16x8 bq0 = *(const u16x8*)(Q + qoff);
  u16x8 bq1 = *(const u16x8*)(Q + qoff + 32);
  // fold 1/sqrt(Dk)=0.125 into Q (exact: exponent shift, low bits stay 0)
#pragma unroll
  for (int j = 0; j < 8; ++j) {
    bq0[j] = (u16)(__builtin_bit_cast(u32, bf2f(bq0[j]) * 0.125f) >> 16);
    bq1[j] = (u16)(__builtin_bit_cast(u32, bf2f(bq1[j]) * 0.125f) >> 16);
  }

  float m = -1e9f, lsum = 0.f;
  f32x4 o[4];
#pragma unroll
  for (int dt = 0; dt < 4; ++dt) o[dt] = (f32x4){0.f, 0.f, 0.f, 0.f};

  const int cdiag = q0 >> 6;
  for (int c = 0; c <= cdiag; ++c) {
    // pad mask for this 64-key chunk as a wave bitmask
    int mv = mask[b * SEQ + (c << 6) + lane];
    u64 bm = __ballot(mv != 0);

    // S^T tile: mfma(A=K, B=Q) -> D[key][q]; lane: col q = lo,
    // rows key = kt*16 + g*4 + r.
    f32x4 s[4];
#pragma unroll
    for (int kt = 0; kt < 4; ++kt) {
      const u16* kp = Kmat + ((size_t)(b * SEQ + (c << 6) + kt * 16 + lo)) * D_MODEL +
                      h * DKH + g * 8;
      u16x8 ak0 = *(const u16x8*)kp;
      u16x8 ak1 = *(const u16x8*)(kp + 32);
      f32x4 z = (f32x4){0.f, 0.f, 0.f, 0.f};
      s[kt] = MFMA(ak0, bq0, z);
      s[kt] = MFMA(ak1, bq1, s[kt]);
    }

    if (bm != ~0ull || c == cdiag) {
#pragma unroll
      for (int kt = 0; kt < 4; ++kt)
#pragma unroll
        for (int r = 0; r < 4; ++r) {
          int kl = kt * 16 + g * 4 + r;
          int kk = (c << 6) + kl;
          if ((kk > qrow) || (((bm >> kl) & 1ull) == 0))
            s[kt][r] = -1e9f;
        }
    }

    // online softmax: lane owns one q; 16 key-scores local
    float cm = s[0][0];
#pragma unroll
    for (int kt = 0; kt < 4; ++kt)
#pragma unroll
      for (int r = 0; r < 4; ++r) cm = fmaxf(cm, s[kt][r]);
    cm = fmaxf(cm, __shfl_xor(cm, 16));
    cm = fmaxf(cm, __shfl_xor(cm, 32));
    float mn = fmaxf(m, cm);
    float fsc = __expf(m - mn);
    m = mn;

    float rs = 0.f;
#pragma unroll
    for (int kt = 0; kt < 4; ++kt) {
      float p0 = __expf(s[kt][0] - mn);
      float p1 = __expf(s[kt][1] - mn);
      float p2 = __expf(s[kt][2] - mn);
      float p3 = __expf(s[kt][3] - mn);
      rs += (p0 + p1) + (p2 + p3);
      // write P[q=lo][key=kt*16+g*4 .. +3] as one ds_write_b64,
      // 16B-chunk XOR swizzle: physchunk = (key>>3) ^ (lo&7)
      u32 w0 = (u32)f2bf(p0) | ((u32)f2bf(p1) << 16);
      u32 w1 = (u32)f2bf(p2) | ((u32)f2bf(p3) << 16);
      int key = kt * 16 + g * 4;
      int byteoff = lo * 144 + ((((key >> 3) ^ (lo & 7)) << 4) | ((key & 7) << 1));
      *(u64*)(P + byteoff) = (u64)w0 | ((u64)w1 << 32);
    }
    rs += __shfl_xor(rs, 16);
    rs += __shfl_xor(rs, 32);
    lsum = lsum * fsc + rs;

    // rescale O rows (row index of o regs = g*4 + r; f lives at lane == row)
#pragma unroll
    for (int r = 0; r < 4; ++r) {
      float fr = __shfl(fsc, (g << 2) + r);
      o[0][r] *= fr;
      o[1][r] *= fr;
      o[2][r] *= fr;
      o[3][r] *= fr;
    }

    // PV: A = P (lane: row q = lo, key = kc*32 + g*8 + j), B = Vt frag
    u16x8 ap0 = *(const u16x8*)(P + lo * 144 + (((0 * 4 + g) ^ (lo & 7)) << 4));
    u16x8 ap1 = *(const u16x8*)(P + lo * 144 + (((4 + g) ^ (lo & 7)) << 4));
#pragma unroll
    for (int dt = 0; dt < 4; ++dt) {
      const u16* vp = Vt + ((size_t)(h * DKH + dt * 16 + lo)) * (NBATCH * SEQ) +
                      b * SEQ + (c << 6) + g * 8;
      u16x8 bv0 = *(const u16x8*)vp;
      u16x8 bv1 = *(const u16x8*)(vp + 32);
      o[dt] = MFMA(ap0, bv0, o[dt]);
      o[dt] = MFMA(ap1, bv1, o[dt]);
    }
  }

  // finalize: divide rows by lsum (held at lane == row), store bf16 ctx
#pragma unroll
  for (int r = 0; r < 4; ++r) {
    float lr = __shfl(lsum, (g << 2) + r);
    float inv = 1.f / lr;
    int row = q0 + wave * 16 + (g << 2) + r;
#pragma unroll
    for (int dt = 0; dt < 4; ++dt) {
      int col = h * DKH + dt * 16 + lo;
      ctx[((size_t)(b * SEQ + row)) * D_MODEL + col] = f2bf(o[dt][r] * inv);
    }
  }
}

// ---------------------------------------------------------------------------
extern "C" void kernel_launch(void* const* d_in, const int* in_sizes, int n_in,
                              void* d_out, int out_size, void* d_ws,
                              size_t ws_size, hipStream_t stream) {
  const float* x = (const float*)d_in[0];
  const int* mask = (const int*)d_in[1];
  const float* Wq = (const float*)d_in[2];
  const float* Wk = (const float*)d_in[3];
  const float* Wv = (const float*)d_in[4];
  const float* Wo = (const float*)d_in[5];
  const float* bo = (const float*)d_in[6];
  float* out = (float*)d_out;

  // workspace layout (bf16 elements); total 46137344 elems = 88 MiB
  u16* xb = (u16*)d_ws;          // 8388608
  u16* wqb = xb + 8388608;       // 1048576
  u16* wkb = wqb + 1048576;
  u16* wvb = wkb + 1048576;
  u16* wob = wvb + 1048576;
  u16* Qm = wob + 1048576;       // 8388608
  u16* Km = Qm + 8388608;        // 8388608
  u16* Vt = Km + 8388608;        // 8388608 (layout: [1024 e][8192 b*S+s])
  u16* ctx = Vt + 8388608;       // 8388608
  if (ws_size < (size_t)46137344 * 2) return;

  conv_all<<<12288, 256, 0, stream>>>(x, Wq, Wk, Wv, Wo, xb, wqb, wkb, wvb, wob);

  // Q = x Wq^T, K = x Wk^T : (8192x1024)
  gemm_bt<0><<<dim3(8, 64), 256, 0, stream>>>(xb, wqb, Qm, nullptr, nullptr,
                                              8192, 1024, 1024);
  gemm_bt<0><<<dim3(8, 64), 256, 0, stream>>>(xb, wkb, Km, nullptr, nullptr,
                                              8192, 1024, 1024);
  // V^T = Wv x^T : (1024x8192)  -- free transpose via operand swap
  gemm_bt<0><<<dim3(64, 8), 256, 0, stream>>>(wvb, xb, Vt, nullptr, nullptr,
                                              1024, 8192, 1024);

  attn_fwd<<<NBATCH * NHEAD * (SEQ / 64), 256, 0, stream>>>(Qm, Km, Vt, mask,
                                                            ctx);

  // out = ctx Wo^T + bo : fp32
  gemm_bt<1><<<dim3(8, 64), 256, 0, stream>>>(ctx, wob, nullptr, out, bo, 8192,
                                              1024, 1024);
}

// Round 4
// 469.205 us; speedup vs baseline: 1.4220x; 1.4220x over previous
//
#include <hip/hip_runtime.h>

typedef unsigned short u16;
typedef unsigned int u32;
typedef unsigned long long u64;
typedef __attribute__((ext_vector_type(8))) u16 u16x8;
typedef __attribute__((ext_vector_type(8))) __bf16 bf16x8;
typedef __attribute__((ext_vector_type(4))) float f32x4;

#define D_MODEL 1024
#define SEQ 2048
#define NBATCH 4
#define NHEAD 16
#define DKH 64

__device__ __forceinline__ u16 f2bf(float f) {
  u32 u = __builtin_bit_cast(u32, f);
  u += 0x7fffu + ((u >> 16) & 1u);   // RTNE
  return (u16)(u >> 16);
}
__device__ __forceinline__ float bf2f(u16 h) {
  u32 u = ((u32)h) << 16;
  return __builtin_bit_cast(float, u);
}
__device__ __forceinline__ f32x4 MFMA(u16x8 a, u16x8 b, f32x4 c) {
  return __builtin_amdgcn_mfma_f32_16x16x32_bf16(
      __builtin_bit_cast(bf16x8, a), __builtin_bit_cast(bf16x8, b), c, 0, 0, 0);
}

#define GLD16(gsrc, ldst)                                                     \
  __builtin_amdgcn_global_load_lds(                                           \
      (const __attribute__((address_space(1))) void*)(gsrc),                  \
      (__attribute__((address_space(3))) void*)(ldst), 16, 0, 0)

// ---------------------------------------------------------------------------
// fp32 -> bf16 conversion for x (8388608 elems) + Wq/Wk/Wv/Wo (1048576 each).
// ---------------------------------------------------------------------------
__global__ __launch_bounds__(256) void conv_all(
    const float* __restrict__ x, const float* __restrict__ wq,
    const float* __restrict__ wk, const float* __restrict__ wv,
    const float* __restrict__ wo, u16* __restrict__ xb, u16* __restrict__ wqb,
    u16* __restrict__ wkb, u16* __restrict__ wvb, u16* __restrict__ wob) {
  long qd = (long)blockIdx.x * 256 + threadIdx.x;
  long e = qd << 2;
  const float* src;
  u16* dst;
  long off;
  if (e < 8388608L) {
    src = x; dst = xb; off = e;
  } else {
    long j = e - 8388608L;
    int w = (int)(j >> 20);
    off = j & 1048575L;
    src = (w == 0) ? wq : (w == 1) ? wk : (w == 2) ? wv : wo;
    dst = (w == 0) ? wqb : (w == 1) ? wkb : (w == 2) ? wvb : wob;
  }
  float4 v = *(const float4*)(src + off);
  u32 lo32 = (u32)f2bf(v.x) | ((u32)f2bf(v.y) << 16);
  u32 hi32 = (u32)f2bf(v.z) | ((u32)f2bf(v.w) << 16);
  *(u64*)(dst + off) = (u64)lo32 | ((u64)hi32 << 32);
}

// ---------------------------------------------------------------------------
// C[M][N] = A[M][K] * Bm[N][K]^T   (m97 structure, unchanged from R0)
// ---------------------------------------------------------------------------
template <int OUTF>
__global__ __launch_bounds__(256) void gemm_bt(
    const u16* __restrict__ A, const u16* __restrict__ Bm, u16* __restrict__ Cb,
    float* __restrict__ Cf, const float* __restrict__ bias, int M, int N,
    int K) {
  __shared__ u16 As[128 * 64];
  __shared__ u16 Bs[128 * 64];
  const int tid = threadIdx.x;
  const int lane = tid & 63, wave = tid >> 6;
  const int lo = lane & 15, g = lane >> 4;
  const int mBase = blockIdx.y * 128, nBase = blockIdx.x * 128;
  const int wr = wave >> 1, wc = wave & 1;

  f32x4 acc[4][4];
#pragma unroll
  for (int mi = 0; mi < 4; ++mi)
#pragma unroll
    for (int ni = 0; ni < 4; ++ni) acc[mi][ni] = (f32x4){0.f, 0.f, 0.f, 0.f};

  const int nK = K >> 6;
  for (int kb = 0; kb < nK; ++kb) {
    __syncthreads();
    const u16* Ab = A + (size_t)mBase * K + kb * 64;
    const u16* Bb = Bm + (size_t)nBase * K + kb * 64;
#pragma unroll
    for (int i = 0; i < 4; ++i) {
      int flat = (i * 256 + tid) * 8;
      int r = flat >> 6, c = flat & 63;
      GLD16(Ab + (size_t)r * K + c, As + (i * 256 + wave * 64) * 8);
    }
#pragma unroll
    for (int i = 0; i < 4; ++i) {
      int flat = (i * 256 + tid) * 8;
      int r = flat >> 6, c = flat & 63;
      GLD16(Bb + (size_t)r * K + c, Bs + (i * 256 + wave * 64) * 8);
    }
    __syncthreads();

#pragma unroll
    for (int kk = 0; kk < 64; kk += 32) {
      u16x8 a[4], b[4];
#pragma unroll
      for (int mi = 0; mi < 4; ++mi)
        a[mi] = *(const u16x8*)&As[(wr * 64 + mi * 16 + lo) * 64 + kk + g * 8];
#pragma unroll
      for (int ni = 0; ni < 4; ++ni)
        b[ni] = *(const u16x8*)&Bs[(wc * 64 + ni * 16 + lo) * 64 + kk + g * 8];
#pragma unroll
      for (int mi = 0; mi < 4; ++mi)
#pragma unroll
        for (int ni = 0; ni < 4; ++ni)
          acc[mi][ni] = MFMA(a[mi], b[ni], acc[mi][ni]);
    }
  }

#pragma unroll
  for (int mi = 0; mi < 4; ++mi)
#pragma unroll
    for (int ni = 0; ni < 4; ++ni) {
      int row0 = mBase + wr * 64 + mi * 16 + g * 4;
      int col = nBase + wc * 64 + ni * 16 + lo;
      float bv = 0.f;
      if constexpr (OUTF == 1) bv = bias[col];
#pragma unroll
      for (int r = 0; r < 4; ++r) {
        size_t idx = (size_t)(row0 + r) * N + col;
        if constexpr (OUTF == 0)
          Cb[idx] = f2bf(acc[mi][ni][r]);
        else
          Cf[idx] = acc[mi][ni][r] + bv;
      }
    }
}

// ---------------------------------------------------------------------------
// Flash attention v2: diagonal-paired q-tiles for perfect balance.
// Block = 4 waves; block handles q-tiles (t, 31-t) sequentially for one
// (b,h) -> every block does exactly 33 chunk-iterations.  K fragments are
// register-prefetched one chunk ahead; mask word prefetched one chunk ahead;
// V loaded direct (issues early, consumed after softmax).  No barriers.
// ---------------------------------------------------------------------------
__global__ __launch_bounds__(256, 4) void attn_fwd(
    const u16* __restrict__ Q, const u16* __restrict__ Kmat,
    const u16* __restrict__ Vt, const int* __restrict__ mask,
    u16* __restrict__ ctx) {
  __shared__ u16 Plds[4][16 * 72];  // per-wave 16 rows x 144B stride
  // XCD grouping: consecutive hardware blockIdx round-robin XCDs; remap so
  // each XCD owns 8 (b,h) groups (K/V working set 8 x 512KB = 4MB = one L2).
  const int bid0 = blockIdx.x;
  const int bid = (bid0 & 7) * 128 + (bid0 >> 3);  // bijective, 1024 = 8*128
  const int pr = bid & 15, h = (bid >> 4) & 15, b = bid >> 8;
  const int tid = threadIdx.x;
  const int lane = tid & 63, wave = tid >> 6;
  const int lo = lane & 15, g = lane >> 4;
  char* P = (char*)&Plds[wave][0];

  u16x8 ak0[4], ak1[4];

#pragma unroll 1
  for (int ti = 0; ti < 2; ++ti) {
    const int t = (ti == 0) ? pr : (31 - pr);
    const int q0 = t << 6;
    const int cdiag = t;
    const int qrow = q0 + wave * 16 + lo;

    // Q fragment (B-operand): lane holds Q[q=lo][dk=g*8+j], x2 for dk 0..63.
    const size_t qoff = ((size_t)(b * SEQ + qrow)) * D_MODEL + h * DKH + g * 8;
    u16x8 bq0 = *(const u16x8*)(Q + qoff);
    u16x8 bq1 = *(const u16x8*)(Q + qoff + 32);
#pragma unroll
    for (int j = 0; j < 8; ++j) {  // fold 1/sqrt(Dk)=0.125 (exact exp shift)
      bq0[j] = (u16)(__builtin_bit_cast(u32, bf2f(bq0[j]) * 0.125f) >> 16);
      bq1[j] = (u16)(__builtin_bit_cast(u32, bf2f(bq1[j]) * 0.125f) >> 16);
    }

    float m = -1e9f, lsum = 0.f;
    f32x4 o[4];
#pragma unroll
    for (int dt = 0; dt < 4; ++dt) o[dt] = (f32x4){0.f, 0.f, 0.f, 0.f};

    // preload K chunk 0 and mask word chunk 0
#pragma unroll
    for (int kt = 0; kt < 4; ++kt) {
      const u16* kp = Kmat + ((size_t)(b * SEQ + kt * 16 + lo)) * D_MODEL +
                      h * DKH + g * 8;
      ak0[kt] = *(const u16x8*)kp;
      ak1[kt] = *(const u16x8*)(kp + 32);
    }
    int mv = mask[b * SEQ + lane];

#pragma unroll 1
    for (int c = 0; c <= cdiag; ++c) {
      u64 bm = __ballot(mv != 0);

      // S^T tile: mfma(A=K, B=Q) -> D[key][q]; lane: col q=lo,
      // rows key = kt*16 + g*4 + r.
      f32x4 s[4];
      __builtin_amdgcn_s_setprio(1);
#pragma unroll
      for (int kt = 0; kt < 4; ++kt) {
        f32x4 z = (f32x4){0.f, 0.f, 0.f, 0.f};
        s[kt] = MFMA(ak0[kt], bq0, z);
        s[kt] = MFMA(ak1[kt], bq1, s[kt]);
      }
      __builtin_amdgcn_s_setprio(0);

      // prefetch K + mask for next chunk (clamped; regs free after S-MFMAs)
      const int cn = (c < cdiag) ? c + 1 : cdiag;
#pragma unroll
      for (int kt = 0; kt < 4; ++kt) {
        const u16* kp = Kmat +
                        ((size_t)(b * SEQ + (cn << 6) + kt * 16 + lo)) * D_MODEL +
                        h * DKH + g * 8;
        ak0[kt] = *(const u16x8*)kp;
        ak1[kt] = *(const u16x8*)(kp + 32);
      }
      mv = mask[b * SEQ + (cn << 6) + lane];

      if (bm != ~0ull || c == cdiag) {
#pragma unroll
        for (int kt = 0; kt < 4; ++kt)
#pragma unroll
          for (int r = 0; r < 4; ++r) {
            int kl = kt * 16 + g * 4 + r;
            int kk = (c << 6) + kl;
            if ((kk > qrow) || (((bm >> kl) & 1ull) == 0)) s[kt][r] = -1e9f;
          }
      }

      // online softmax: lane owns q-row lo; 16 key-scores local
      float cm = s[0][0];
#pragma unroll
      for (int kt = 0; kt < 4; ++kt)
#pragma unroll
        for (int r = 0; r < 4; ++r) cm = fmaxf(cm, s[kt][r]);
      cm = fmaxf(cm, __shfl_xor(cm, 16));
      cm = fmaxf(cm, __shfl_xor(cm, 32));
      float mn = fmaxf(m, cm);
      float fsc = __expf(m - mn);
      m = mn;

      float rs = 0.f;
#pragma unroll
      for (int kt = 0; kt < 4; ++kt) {
        float p0 = __expf(s[kt][0] - mn);
        float p1 = __expf(s[kt][1] - mn);
        float p2 = __expf(s[kt][2] - mn);
        float p3 = __expf(s[kt][3] - mn);
        rs += (p0 + p1) + (p2 + p3);
        // P[q=lo][key=kt*16+g*4..+3] as one ds_write_b64; 16B-chunk XOR
        // swizzle: physchunk = (key>>3) ^ (lo&7)
        u32 w0 = (u32)f2bf(p0) | ((u32)f2bf(p1) << 16);
        u32 w1 = (u32)f2bf(p2) | ((u32)f2bf(p3) << 16);
        int key = kt * 16 + g * 4;
        int byteoff =
            lo * 144 + ((((key >> 3) ^ (lo & 7)) << 4) | ((key & 7) << 1));
        *(u64*)(P + byteoff) = (u64)w0 | ((u64)w1 << 32);
      }
      rs += __shfl_xor(rs, 16);
      rs += __shfl_xor(rs, 32);
      lsum = lsum * fsc + rs;

      // rescale O rows (row index of o regs = g*4+r; fsc lives at lane==row)
#pragma unroll
      for (int r = 0; r < 4; ++r) {
        float fr = __shfl(fsc, (g << 2) + r);
        o[0][r] *= fr;
        o[1][r] *= fr;
        o[2][r] *= fr;
        o[3][r] *= fr;
      }

      // PV: A = P (lane: row q=lo, key=g*8+j / 32+g*8+j), B = Vt frag
      u16x8 ap0 = *(const u16x8*)(P + lo * 144 + ((g ^ (lo & 7)) << 4));
      u16x8 ap1 = *(const u16x8*)(P + lo * 144 + (((4 + g) ^ (lo & 7)) << 4));
      __builtin_amdgcn_s_setprio(1);
#pragma unroll
      for (int dt = 0; dt < 4; ++dt) {
        const u16* vp = Vt +
                        ((size_t)(h * DKH + dt * 16 + lo)) * (NBATCH * SEQ) +
                        b * SEQ + (c << 6) + g * 8;
        u16x8 bv0 = *(const u16x8*)vp;
        u16x8 bv1 = *(const u16x8*)(vp + 32);
        o[dt] = MFMA(ap0, bv0, o[dt]);
        o[dt] = MFMA(ap1, bv1, o[dt]);
      }
      __builtin_amdgcn_s_setprio(0);
    }

    // finalize: divide rows by lsum (held at lane==row), store bf16 ctx
#pragma unroll
    for (int r = 0; r < 4; ++r) {
      float lr = __shfl(lsum, (g << 2) + r);
      float inv = 1.f / lr;
      int row = q0 + wave * 16 + (g << 2) + r;
#pragma unroll
      for (int dt = 0; dt < 4; ++dt) {
        int col = h * DKH + dt * 16 + lo;
        ctx[((size_t)(b * SEQ + row)) * D_MODEL + col] = f2bf(o[dt][r] * inv);
      }
    }
  }
}

// ---------------------------------------------------------------------------
extern "C" void kernel_launch(void* const* d_in, const int* in_sizes, int n_in,
                              void* d_out, int out_size, void* d_ws,
                              size_t ws_size, hipStream_t stream) {
  const float* x = (const float*)d_in[0];
  const int* mask = (const int*)d_in[1];
  const float* Wq = (const float*)d_in[2];
  const float* Wk = (const float*)d_in[3];
  const float* Wv = (const float*)d_in[4];
  const float* Wo = (const float*)d_in[5];
  const float* bo = (const float*)d_in[6];
  float* out = (float*)d_out;

  // workspace layout (bf16 elements); total 46137344 elems = 88 MiB
  u16* xb = (u16*)d_ws;          // 8388608
  u16* wqb = xb + 8388608;       // 1048576
  u16* wkb = wqb + 1048576;
  u16* wvb = wkb + 1048576;
  u16* wob = wvb + 1048576;
  u16* Qm = wob + 1048576;       // 8388608
  u16* Km = Qm + 8388608;        // 8388608
  u16* Vt = Km + 8388608;        // 8388608 (layout: [1024 e][8192 b*S+s])
  u16* ctx = Vt + 8388608;       // 8388608
  if (ws_size < (size_t)46137344 * 2) return;

  conv_all<<<12288, 256, 0, stream>>>(x, Wq, Wk, Wv, Wo, xb, wqb, wkb, wvb, wob);

  // Q = x Wq^T, K = x Wk^T : (8192x1024)
  gemm_bt<0><<<dim3(8, 64), 256, 0, stream>>>(xb, wqb, Qm, nullptr, nullptr,
                                              8192, 1024, 1024);
  gemm_bt<0><<<dim3(8, 64), 256, 0, stream>>>(xb, wkb, Km, nullptr, nullptr,
                                              8192, 1024, 1024);
  // V^T = Wv x^T : (1024x8192)  -- free transpose via operand swap
  gemm_bt<0><<<dim3(64, 8), 256, 0, stream>>>(wvb, xb, Vt, nullptr, nullptr,
                                              1024, 8192, 1024);

  attn_fwd<<<1024, 256, 0, stream>>>(Qm, Km, Vt, mask, ctx);

  // out = ctx Wo^T + bo : fp32
  gemm_bt<1><<<dim3(8, 64), 256, 0, stream>>>(ctx, wob, nullptr, out, bo, 8192,
                                              1024, 1024);
}